// Round 3
// baseline (283.472 us; speedup 1.0000x reference)
//
#include <hip/hip_runtime.h>
#include <hip/hip_bf16.h>

#define B_TOK 8192
#define D_DIM 3072
#define H_DIM 128
#define O_DIM 10
#define N_EXP 8

#define BM 128
#define BK 64
#define HLDS_STRIDE 136   // bf16 elems; row byte stride 272

typedef __bf16 bf16x8 __attribute__((ext_vector_type(8)));
typedef float  f32x4  __attribute__((ext_vector_type(4)));

// fp32 -> bf16 round-to-nearest-even
__device__ __forceinline__ unsigned short f2bf(float f) {
  unsigned int u = __float_as_uint(f);
  unsigned int r = (u + 0x7FFFu + ((u >> 16) & 1u)) >> 16;
  return (unsigned short)r;
}

__device__ __forceinline__ void async16(const void* g, void* l) {
  __builtin_amdgcn_global_load_lds(
      (const __attribute__((address_space(1))) void*)g,
      (__attribute__((address_space(3))) void*)l,
      16, 0, 0);
}

// ---------------- K0: W1 [8][3072][128] fp32 -> W1^T [8][128][3072] bf16 ----------------
__global__ void k0_w1_transpose(const float* __restrict__ W1,
                                unsigned short* __restrict__ w1t) {
  __shared__ unsigned short tile[32][33];
  const int e  = blockIdx.z;
  const int d0 = blockIdx.x * 32;
  const int h0 = blockIdx.y * 32;
  const int tx = threadIdx.x;   // 0..31
  const int ty = threadIdx.y;   // 0..7
  const float* src = W1 + ((size_t)e * D_DIM + d0) * H_DIM + h0;
#pragma unroll
  for (int k = 0; k < 4; ++k) {
    int r = ty + 8 * k;
    tile[r][tx] = f2bf(src[(size_t)r * H_DIM + tx]);
  }
  __syncthreads();
  unsigned short* dst = w1t + ((size_t)e * H_DIM + h0) * D_DIM + d0;
#pragma unroll
  for (int k = 0; k < 4; ++k) {
    int r = ty + 8 * k;
    dst[(size_t)r * D_DIM + tx] = tile[tx][r];
  }
}

// ---------------- K1: x -> bf16, fp32 gating, top-2 + softmax, count/pos build ----------------
// 512 threads (8 waves), 4 tokens per wave -> 8 LDS reads feed 32 FMAs.
__global__ __launch_bounds__(512) void k1_gate_convert(
    const float* __restrict__ x, const float* __restrict__ Wg,
    const float* __restrict__ bg, unsigned short* __restrict__ xb,
    int4* __restrict__ idx4, float2* __restrict__ wts, int* __restrict__ cnt) {
  __shared__ float wg_lds[N_EXP * D_DIM];  // 96 KB, [n][d]
  __shared__ int lcnt[N_EXP], gbase[N_EXP];
  const int tid = threadIdx.x;

  if (tid < N_EXP) lcnt[tid] = 0;
  // stage Wg [D][N] row-major -> lds [n][d], float4 global reads
  for (int f = tid; f < D_DIM * N_EXP / 4; f += 512) {
    const float4 v = ((const float4*)Wg)[f];
    const int d  = f >> 1;
    const int nh = (f & 1) * 4;
    wg_lds[(nh + 0) * D_DIM + d] = v.x;
    wg_lds[(nh + 1) * D_DIM + d] = v.y;
    wg_lds[(nh + 2) * D_DIM + d] = v.z;
    wg_lds[(nh + 3) * D_DIM + d] = v.w;
  }
  __syncthreads();

  const int lane = tid & 63;
  const int wv   = tid >> 6;          // 0..7
  const int tk0  = blockIdx.x * 32 + wv * 4;

  const float* xr0 = x + (size_t)(tk0 + 0) * D_DIM;
  const float* xr1 = x + (size_t)(tk0 + 1) * D_DIM;
  const float* xr2 = x + (size_t)(tk0 + 2) * D_DIM;
  const float* xr3 = x + (size_t)(tk0 + 3) * D_DIM;
  unsigned short* xw0 = xb + (size_t)(tk0 + 0) * D_DIM;
  unsigned short* xw1 = xb + (size_t)(tk0 + 1) * D_DIM;
  unsigned short* xw2 = xb + (size_t)(tk0 + 2) * D_DIM;
  unsigned short* xw3 = xb + (size_t)(tk0 + 3) * D_DIM;

  float acc[4][N_EXP];
#pragma unroll
  for (int t = 0; t < 4; ++t)
#pragma unroll
    for (int n = 0; n < N_EXP; ++n) acc[t][n] = 0.f;

#pragma unroll 2
  for (int jj = 0; jj < D_DIM / 64; ++jj) {
    const int d = jj * 64 + lane;
    float w8[N_EXP];
#pragma unroll
    for (int n = 0; n < N_EXP; ++n) w8[n] = wg_lds[n * D_DIM + d];
    const float x0 = xr0[d], x1 = xr1[d], x2 = xr2[d], x3 = xr3[d];
    xw0[d] = f2bf(x0); xw1[d] = f2bf(x1); xw2[d] = f2bf(x2); xw3[d] = f2bf(x3);
#pragma unroll
    for (int n = 0; n < N_EXP; ++n) {
      acc[0][n] = fmaf(x0, w8[n], acc[0][n]);
      acc[1][n] = fmaf(x1, w8[n], acc[1][n]);
      acc[2][n] = fmaf(x2, w8[n], acc[2][n]);
      acc[3][n] = fmaf(x3, w8[n], acc[3][n]);
    }
  }

#pragma unroll
  for (int t = 0; t < 4; ++t)
#pragma unroll
    for (int n = 0; n < N_EXP; ++n) {
#pragma unroll
      for (int off = 32; off > 0; off >>= 1)
        acc[t][n] += __shfl_xor(acc[t][n], off, 64);
    }

  int li0[4], li1[4], lp0[4], lp1[4];
  float lw0[4], lw1[4];
  if (lane == 0) {
#pragma unroll
    for (int t = 0; t < 4; ++t) {
      float g[N_EXP];
#pragma unroll
      for (int n = 0; n < N_EXP; ++n) g[n] = acc[t][n] + bg[n];
      int i0 = 0;
#pragma unroll
      for (int n = 1; n < N_EXP; ++n) if (g[n] > g[i0]) i0 = n;
      int i1 = (i0 == 0) ? 1 : 0;
#pragma unroll
      for (int n = 0; n < N_EXP; ++n) if (n != i0 && g[n] > g[i1]) i1 = n;
      float e1 = expf(g[i1] - g[i0]);
      float inv = 1.f / (1.f + e1);
      li0[t] = i0; li1[t] = i1;
      lw0[t] = inv; lw1[t] = e1 * inv;
      lp0[t] = atomicAdd(&lcnt[i0], 1);
      lp1[t] = atomicAdd(&lcnt[i1], 1);
    }
  }
  __syncthreads();
  if (tid < N_EXP) gbase[tid] = atomicAdd(&cnt[tid], lcnt[tid]);
  __syncthreads();
  if (lane == 0) {
#pragma unroll
    for (int t = 0; t < 4; ++t) {
      idx4[tk0 + t] = make_int4(li0[t], gbase[li0[t]] + lp0[t],
                                li1[t], gbase[li1[t]] + lp1[t]);
      wts[tk0 + t]  = make_float2(lw0[t], lw1[t]);
    }
  }
}

// ---------------- K1b: prefix-sum counts, scatter token list ----------------
__global__ __launch_bounds__(256) void k1b_scan_scatter(
    const int* __restrict__ cnt, int* __restrict__ off_g,
    const int4* __restrict__ idx4, int* __restrict__ tlist) {
  __shared__ int off[N_EXP + 1];
  if (threadIdx.x == 0) {
    int s = 0;
#pragma unroll
    for (int n = 0; n < N_EXP; ++n) { off[n] = s; s += cnt[n]; }
    off[N_EXP] = s;
#pragma unroll
    for (int n = 0; n <= N_EXP; ++n) off_g[n] = off[n];
  }
  __syncthreads();
  for (int t = threadIdx.x; t < B_TOK; t += 256) {
    const int4 r = idx4[t];
    tlist[off[r.x] + r.y] = t;
    tlist[off[r.z] + r.w] = t;
  }
}

// ---------------- K2: sparse per-expert h=relu(x@W1+b1); y=h@W2+b2 -> ypair ----------------
__global__ __launch_bounds__(256) void k2_experts(
    const unsigned short* __restrict__ xb,    // [B][D] bf16
    const unsigned short* __restrict__ w1t,   // [N][H][D] bf16
    const float* __restrict__ b1,             // [N][H]
    const float* __restrict__ W2,             // [N][H][O]
    const float* __restrict__ b2,             // [N][O]
    const int* __restrict__ cnt, const int* __restrict__ off_g,
    const int* __restrict__ tlist,
    float* __restrict__ ypair) {              // [16384][16]
  const int e    = blockIdx.y;
  const int n_e  = cnt[e];
  const int row0 = blockIdx.x * BM;
  if (row0 >= n_e) return;
  const int off_e = off_g[e];

  __shared__ __align__(16) unsigned short sm[(34816 + 4096) / 2];
  unsigned short* a_lds   = sm;
  unsigned short* b_lds   = sm + 128 * 64;
  unsigned short* h_lds   = sm;
  unsigned short* w2t_lds = sm + 128 * HLDS_STRIDE;

  const int tid  = threadIdx.x;
  const int lane = tid & 63;
  const int wv   = tid >> 6;

  // stage W2^T (o-major, k=h contiguous) as bf16; o padded to 16
  const float* W2e = W2 + (size_t)e * H_DIM * O_DIM;
  for (int idx = tid; idx < 16 * 128; idx += 256) {
    int o = idx >> 7, hh = idx & 127;
    float v = (o < O_DIM) ? W2e[hh * O_DIM + o] : 0.f;
    w2t_lds[idx] = f2bf(v);
  }

  const int mhalf = (wv >> 1) * 64;
  const int nhalf = (wv & 1) * 64;

  f32x4 acc[4][4];
#pragma unroll
  for (int i = 0; i < 4; ++i)
#pragma unroll
    for (int j = 0; j < 4; ++j)
      acc[i][j] = (f32x4){0.f, 0.f, 0.f, 0.f};

  const int srow = wv * 32 + (lane >> 3);   // staging row (+ j*8)
  const int scol = (lane & 7) * 8;          // staging k-elem offset

  // gather A-row pointers through the token list (clamped for partial tiles)
  const unsigned short* Arow[4];
#pragma unroll
  for (int j = 0; j < 4; ++j) {
    int gr = row0 + srow + j * 8;
    gr = gr < n_e ? gr : n_e - 1;
    Arow[j] = xb + (size_t)tlist[off_e + gr] * D_DIM + scol;
  }
  const unsigned short* Bt_base = w1t + (size_t)e * H_DIM * D_DIM + scol;

  for (int k0 = 0; k0 < D_DIM; k0 += BK) {
#pragma unroll
    for (int j = 0; j < 4; ++j) {
      const int r = srow + j * 8;
      async16(Arow[j] + k0, a_lds + (wv * 32 + j * 8) * BK);
      async16(Bt_base + (size_t)r * D_DIM + k0, b_lds + (wv * 32 + j * 8) * BK);
    }
    __syncthreads();
#pragma unroll
    for (int kk = 0; kk < 2; ++kk) {
      bf16x8 af[4], bfr[4];
      const int krd = kk * 32 + (lane >> 4) * 8;
#pragma unroll
      for (int mi = 0; mi < 4; ++mi)
        af[mi] = *(const bf16x8*)(a_lds + (mhalf + mi * 16 + (lane & 15)) * BK + krd);
#pragma unroll
      for (int ni = 0; ni < 4; ++ni)
        bfr[ni] = *(const bf16x8*)(b_lds + (nhalf + ni * 16 + (lane & 15)) * BK + krd);
#pragma unroll
      for (int mi = 0; mi < 4; ++mi)
#pragma unroll
        for (int ni = 0; ni < 4; ++ni)
          acc[mi][ni] = __builtin_amdgcn_mfma_f32_16x16x32_bf16(af[mi], bfr[ni], acc[mi][ni], 0, 0, 0);
    }
    __syncthreads();
  }

  // epilogue 1: h = relu(acc + b1) -> h_lds (bf16). C/D layout: col=lane&15, row=quad*4+r
  const float* b1e = b1 + e * H_DIM;
#pragma unroll
  for (int ni = 0; ni < 4; ++ni) {
    const int col  = nhalf + ni * 16 + (lane & 15);
    const float bias = b1e[col];
#pragma unroll
    for (int mi = 0; mi < 4; ++mi) {
      const int rbase = mhalf + mi * 16 + ((lane >> 4) << 2);
#pragma unroll
      for (int r = 0; r < 4; ++r) {
        float v = acc[mi][ni][r] + bias;
        v = v > 0.f ? v : 0.f;
        h_lds[(rbase + r) * HLDS_STRIDE + col] = f2bf(v);
      }
    }
  }
  __syncthreads();

  // epilogue 2: y[128x16] = h[128x128] @ W2[128x16]; wave handles 32 token rows
  f32x4 acc2[2];
  acc2[0] = (f32x4){0.f, 0.f, 0.f, 0.f};
  acc2[1] = (f32x4){0.f, 0.f, 0.f, 0.f};
#pragma unroll
  for (int ks = 0; ks < 4; ++ks) {
    const int krd = ks * 32 + (lane >> 4) * 8;
    bf16x8 bfr = *(const bf16x8*)(w2t_lds + (lane & 15) * 128 + krd);
#pragma unroll
    for (int mi = 0; mi < 2; ++mi) {
      bf16x8 afr = *(const bf16x8*)(h_lds + (wv * 32 + mi * 16 + (lane & 15)) * HLDS_STRIDE + krd);
      acc2[mi] = __builtin_amdgcn_mfma_f32_16x16x32_bf16(afr, bfr, acc2[mi], 0, 0, 0);
    }
  }
  const int o = lane & 15;
  if (o < O_DIM) {
    const float bias2 = b2[e * O_DIM + o];
#pragma unroll
    for (int mi = 0; mi < 2; ++mi) {
#pragma unroll
      for (int r = 0; r < 4; ++r) {
        const int rl = wv * 32 + mi * 16 + ((lane >> 4) << 2) + r;
        if (row0 + rl < n_e)
          ypair[(size_t)(off_e + row0 + rl) * 16 + o] = acc2[mi][r] + bias2;
      }
    }
  }
}

// ---------------- K3: combine top-2 via compact slots ----------------
__global__ __launch_bounds__(256) void k3_combine(
    const float* __restrict__ ypair, const int4* __restrict__ idx4,
    const float2* __restrict__ wts, const int* __restrict__ off_g,
    float* __restrict__ out) {
  const int g = blockIdx.x * 256 + threadIdx.x;
  if (g >= B_TOK * O_DIM) return;
  const int b = g / O_DIM, o = g - b * O_DIM;
  const int4 r = idx4[b];
  const float2 w = wts[b];
  out[g] = w.x * ypair[(size_t)(off_g[r.x] + r.y) * 16 + o] +
           w.y * ypair[(size_t)(off_g[r.z] + r.w) * 16 + o];
}

extern "C" void kernel_launch(void* const* d_in, const int* in_sizes, int n_in,
                              void* d_out, int out_size, void* d_ws, size_t ws_size,
                              hipStream_t stream) {
  const float* x  = (const float*)d_in[0];
  const float* Wg = (const float*)d_in[1];
  const float* bg = (const float*)d_in[2];
  const float* W1 = (const float*)d_in[3];
  const float* b1 = (const float*)d_in[4];
  const float* W2 = (const float*)d_in[5];
  const float* b2 = (const float*)d_in[6];
  float* out = (float*)d_out;

  char* ws = (char*)d_ws;
  unsigned short* xb  = (unsigned short*)ws;                 // 50331648
  unsigned short* w1t = (unsigned short*)(ws + 50331648);    // 6291456
  int4*   idx4  = (int4*)  (ws + 56623104);                  // 131072
  float2* wts   = (float2*)(ws + 56754176);                  // 65536
  int*    cnt   = (int*)   (ws + 56819712);                  // 32
  int*    off_g = (int*)   (ws + 56819744);                  // 96 (pad)
  int*    tlist = (int*)   (ws + 56819840);                  // 65536
  float*  ypair = (float*) (ws + 56885376);                  // 1048576

  k0_w1_transpose<<<dim3(96, 4, 8), dim3(32, 8), 0, stream>>>(W1, w1t);
  hipMemsetAsync(cnt, 0, N_EXP * sizeof(int), stream);
  k1_gate_convert<<<dim3(B_TOK / 32), dim3(512), 0, stream>>>(x, Wg, bg, xb, idx4, wts, cnt);
  k1b_scan_scatter<<<dim3(1), dim3(256), 0, stream>>>(cnt, off_g, idx4, tlist);
  k2_experts<<<dim3(B_TOK / BM, N_EXP), dim3(256), 0, stream>>>(
      xb, w1t, b1, W2, b2, cnt, off_g, tlist, ypair);
  k3_combine<<<dim3((B_TOK * O_DIM + 255) / 256), dim3(256), 0, stream>>>(
      ypair, idx4, wts, off_g, out);
}

// Round 5
// 270.615 us; speedup vs baseline: 1.0475x; 1.0475x over previous
//
#include <hip/hip_runtime.h>
#include <hip/hip_bf16.h>

#define B_TOK 8192
#define D_DIM 3072
#define H_DIM 128
#define O_DIM 10
#define N_EXP 8

#define BM 128
#define BK2 128            // K-tile (24 iters over D=3072)
#define HLDS_STRIDE 136    // bf16 elems; row byte stride 272

typedef __bf16 bf16x8 __attribute__((ext_vector_type(8)));
typedef float  f32x4  __attribute__((ext_vector_type(4)));
typedef unsigned short us8 __attribute__((ext_vector_type(8)));

// fp32 -> bf16 round-to-nearest-even
__device__ __forceinline__ unsigned short f2bf(float f) {
  unsigned int u = __float_as_uint(f);
  unsigned int r = (u + 0x7FFFu + ((u >> 16) & 1u)) >> 16;
  return (unsigned short)r;
}

__device__ __forceinline__ void async16(const void* g, void* l) {
  __builtin_amdgcn_global_load_lds(
      (const __attribute__((address_space(1))) void*)g,
      (__attribute__((address_space(3))) void*)l,
      16, 0, 0);
}

// ---------------- K0: W1 [8][3072][128] fp32 -> W1^T [8][128][3072] bf16 ----------------
// 64x64 tiles; 256B coalesced loads, LDS transpose, 16B/lane ushort8 stores.
__global__ __launch_bounds__(256) void k0_w1_transpose(const float* __restrict__ W1,
                                                       unsigned short* __restrict__ w1t) {
  __shared__ __align__(16) unsigned short lds[64 * 72];  // [h][72]
  const int e  = blockIdx.z;
  const int d0 = blockIdx.x * 64;
  const int h0 = blockIdx.y * 64;
  const int tid = threadIdx.x;

  const float* src = W1 + ((size_t)e * D_DIM + d0) * H_DIM + h0;
  const int hl = tid & 63;   // h lane
  const int dg = tid >> 6;   // 0..3
#pragma unroll
  for (int k = 0; k < 16; ++k) {
    const int d = dg + 4 * k;
    lds[hl * 72 + d] = f2bf(src[(size_t)d * H_DIM + hl]);
  }
  __syncthreads();

  unsigned short* dst = w1t + ((size_t)e * H_DIM + h0) * D_DIM + d0;
  const int q  = tid & 7;    // d-oct
  const int h1 = tid >> 3;   // 0..31
#pragma unroll
  for (int k = 0; k < 2; ++k) {
    const int h = h1 + 32 * k;
    const int d = q * 8;
    us8 v = *(const us8*)(lds + h * 72 + d);
    *(us8*)(dst + (size_t)h * D_DIM + d) = v;
  }
}

// ---------------- K1: x -> bf16, fp32 gating, top-2 + softmax, count/pos build ----------------
__global__ __launch_bounds__(512) void k1_gate_convert(
    const float* __restrict__ x, const float* __restrict__ Wg,
    const float* __restrict__ bg, unsigned short* __restrict__ xb,
    int4* __restrict__ idx4, float2* __restrict__ wts, int* __restrict__ cnt) {
  __shared__ float wg_lds[N_EXP * D_DIM];  // 96 KB, [n][d]
  __shared__ int lcnt[N_EXP], gbase[N_EXP];
  const int tid = threadIdx.x;

  if (tid < N_EXP) lcnt[tid] = 0;
  for (int f = tid; f < D_DIM * N_EXP / 4; f += 512) {
    const float4 v = ((const float4*)Wg)[f];
    const int d  = f >> 1;
    const int nh = (f & 1) * 4;
    wg_lds[(nh + 0) * D_DIM + d] = v.x;
    wg_lds[(nh + 1) * D_DIM + d] = v.y;
    wg_lds[(nh + 2) * D_DIM + d] = v.z;
    wg_lds[(nh + 3) * D_DIM + d] = v.w;
  }
  __syncthreads();

  const int lane = tid & 63;
  const int wv   = tid >> 6;          // 0..7
  const int tk0  = blockIdx.x * 32 + wv * 4;

  const float* xr0 = x + (size_t)(tk0 + 0) * D_DIM;
  const float* xr1 = x + (size_t)(tk0 + 1) * D_DIM;
  const float* xr2 = x + (size_t)(tk0 + 2) * D_DIM;
  const float* xr3 = x + (size_t)(tk0 + 3) * D_DIM;
  unsigned short* xw0 = xb + (size_t)(tk0 + 0) * D_DIM;
  unsigned short* xw1 = xb + (size_t)(tk0 + 1) * D_DIM;
  unsigned short* xw2 = xb + (size_t)(tk0 + 2) * D_DIM;
  unsigned short* xw3 = xb + (size_t)(tk0 + 3) * D_DIM;

  float acc[4][N_EXP];
#pragma unroll
  for (int t = 0; t < 4; ++t)
#pragma unroll
    for (int n = 0; n < N_EXP; ++n) acc[t][n] = 0.f;

#pragma unroll 2
  for (int jj = 0; jj < D_DIM / 64; ++jj) {
    const int d = jj * 64 + lane;
    float w8[N_EXP];
#pragma unroll
    for (int n = 0; n < N_EXP; ++n) w8[n] = wg_lds[n * D_DIM + d];
    const float x0 = xr0[d], x1 = xr1[d], x2 = xr2[d], x3 = xr3[d];
    xw0[d] = f2bf(x0); xw1[d] = f2bf(x1); xw2[d] = f2bf(x2); xw3[d] = f2bf(x3);
#pragma unroll
    for (int n = 0; n < N_EXP; ++n) {
      acc[0][n] = fmaf(x0, w8[n], acc[0][n]);
      acc[1][n] = fmaf(x1, w8[n], acc[1][n]);
      acc[2][n] = fmaf(x2, w8[n], acc[2][n]);
      acc[3][n] = fmaf(x3, w8[n], acc[3][n]);
    }
  }

#pragma unroll
  for (int t = 0; t < 4; ++t)
#pragma unroll
    for (int n = 0; n < N_EXP; ++n) {
#pragma unroll
      for (int off = 32; off > 0; off >>= 1)
        acc[t][n] += __shfl_xor(acc[t][n], off, 64);
    }

  int li0[4], li1[4], lp0[4], lp1[4];
  float lw0[4], lw1[4];
  if (lane == 0) {
#pragma unroll
    for (int t = 0; t < 4; ++t) {
      float g[N_EXP];
#pragma unroll
      for (int n = 0; n < N_EXP; ++n) g[n] = acc[t][n] + bg[n];
      int i0 = 0;
#pragma unroll
      for (int n = 1; n < N_EXP; ++n) if (g[n] > g[i0]) i0 = n;
      int i1 = (i0 == 0) ? 1 : 0;
#pragma unroll
      for (int n = 0; n < N_EXP; ++n) if (n != i0 && g[n] > g[i1]) i1 = n;
      float e1 = expf(g[i1] - g[i0]);
      float inv = 1.f / (1.f + e1);
      li0[t] = i0; li1[t] = i1;
      lw0[t] = inv; lw1[t] = e1 * inv;
      lp0[t] = atomicAdd(&lcnt[i0], 1);
      lp1[t] = atomicAdd(&lcnt[i1], 1);
    }
  }
  __syncthreads();
  if (tid < N_EXP) gbase[tid] = atomicAdd(&cnt[tid], lcnt[tid]);
  __syncthreads();
  if (lane == 0) {
#pragma unroll
    for (int t = 0; t < 4; ++t) {
      idx4[tk0 + t] = make_int4(li0[t], gbase[li0[t]] + lp0[t],
                                li1[t], gbase[li1[t]] + lp1[t]);
      wts[tk0 + t]  = make_float2(lw0[t], lw1[t]);
    }
  }
}

// ---------------- K1b1: tiny scan (offsets padded to BM) ----------------
__global__ void k1b1_scan(const int* __restrict__ cnt, int* __restrict__ off_g) {
  if (threadIdx.x == 0) {
    int s = 0;
#pragma unroll
    for (int n = 0; n < N_EXP; ++n) {
      off_g[n] = s;
      s += (cnt[n] + BM - 1) / BM * BM;   // pad each expert region to BM
    }
    off_g[N_EXP] = s;
  }
}

// ---------------- K1b2: scatter token list ----------------
__global__ __launch_bounds__(256) void k1b2_scatter(
    const int* __restrict__ off_g, const int4* __restrict__ idx4,
    int* __restrict__ tlist) {
  const int t = blockIdx.x * 256 + threadIdx.x;
  if (t >= B_TOK) return;
  const int4 r = idx4[t];
  tlist[off_g[r.x] + r.y] = t;
  tlist[off_g[r.z] + r.w] = t;
}

// ---------------- K2: sparse per-expert h=relu(x@W1+b1); y=h@W2+b2 -> ypair ----------------
// BK=128, double-buffered LDS prefetch (depth 1). Ping-pong via byte offsets
// (NO arrays of LDS pointers — gfx950 rejects the addrspacecast initializer).
__global__ __launch_bounds__(256) void k2_experts(
    const unsigned short* __restrict__ xb,    // [B][D] bf16
    const unsigned short* __restrict__ w1t,   // [N][H][D] bf16
    const float* __restrict__ b1,             // [N][H]
    const float* __restrict__ W2,             // [N][H][O]
    const float* __restrict__ b2,             // [N][O]
    const int* __restrict__ cnt, const int* __restrict__ off_g,
    const int* __restrict__ tlist,
    float* __restrict__ ypair) {              // [padded slots][16]
  const int e    = blockIdx.y;
  const int n_e  = cnt[e];
  const int row0 = blockIdx.x * BM;
  if (row0 >= n_e) return;
  const int off_e = off_g[e];

  // LDS: buf0 A|B (64KB) + buf1 A|B (64KB) + w2t (4KB); h (34.8KB) overlays buf0
  __shared__ __align__(16) unsigned short sm[65536 + 2048];
  unsigned short* h_lds   = sm;
  unsigned short* w2t_lds = sm + 65536;

  const int tid  = threadIdx.x;
  const int lane = tid & 63;
  const int wv   = tid >> 6;

  // stage W2^T (o-major, k=h contiguous) as bf16; o padded to 16
  const float* W2e = W2 + (size_t)e * H_DIM * O_DIM;
  for (int idx = tid; idx < 16 * 128; idx += 256) {
    int o = idx >> 7, hh = idx & 127;
    float v = (o < O_DIM) ? W2e[hh * O_DIM + o] : 0.f;
    w2t_lds[idx] = f2bf(v);
  }

  const int mhalf = (wv >> 1) * 64;
  const int nhalf = (wv & 1) * 64;

  f32x4 acc[4][4];
#pragma unroll
  for (int i = 0; i < 4; ++i)
#pragma unroll
    for (int j = 0; j < 4; ++j)
      acc[i][j] = (f32x4){0.f, 0.f, 0.f, 0.f};

  // staging assignment: wave wv, instr j (0..7): rows wv*32 + j*4 + (lane>>4),
  // k-cols (lane&15)*8 .. +7 ; each async16 stages a [4][128] chunk (1KB/wave-instr)
  const int quad = lane >> 4;
  const int koff0 = (lane & 15) * 8;
  const unsigned short* Abase[8];
  const unsigned short* Bbase[8];
#pragma unroll
  for (int j = 0; j < 8; ++j) {
    int rloc = wv * 32 + j * 4 + quad;
    int gr = row0 + rloc;
    gr = gr < n_e ? gr : n_e - 1;
    Abase[j] = xb + (size_t)tlist[off_e + gr] * D_DIM + koff0;
    Bbase[j] = w1t + ((size_t)e * H_DIM + rloc) * D_DIM + koff0;
  }

  // buffer `pp` (0/1): A at sm + pp*32768, B at sm + 16384 + pp*32768
#define STAGE(it, pp)                                                     \
  {                                                                       \
    const int ko = (it) * BK2;                                            \
    unsigned short* abuf = sm + (pp) * 32768;                             \
    unsigned short* bbuf = sm + 16384 + (pp) * 32768;                     \
    _Pragma("unroll")                                                     \
    for (int j = 0; j < 8; ++j) {                                         \
      const int ldsrow = (wv * 32 + j * 4) * BK2;                         \
      async16(Abase[j] + ko, abuf + ldsrow);                              \
      async16(Bbase[j] + ko, bbuf + ldsrow);                              \
    }                                                                     \
  }

  STAGE(0, 0);

  const int NIT = D_DIM / BK2;  // 24
  for (int it = 0; it < NIT; ++it) {
    __syncthreads();                       // drains: buf[it&1] ready
    if (it + 1 < NIT) STAGE(it + 1, (it + 1) & 1);
    const unsigned short* al = sm + (it & 1) * 32768;
    const unsigned short* bl = sm + 16384 + (it & 1) * 32768;
#pragma unroll
    for (int kk = 0; kk < 4; ++kk) {
      const int krd = kk * 32 + quad * 8;
      bf16x8 af[4], bfr[4];
#pragma unroll
      for (int mi = 0; mi < 4; ++mi)
        af[mi] = *(const bf16x8*)(al + (mhalf + mi * 16 + (lane & 15)) * BK2 + krd);
#pragma unroll
      for (int ni = 0; ni < 4; ++ni)
        bfr[ni] = *(const bf16x8*)(bl + (nhalf + ni * 16 + (lane & 15)) * BK2 + krd);
#pragma unroll
      for (int mi = 0; mi < 4; ++mi)
#pragma unroll
        for (int ni = 0; ni < 4; ++ni)
          acc[mi][ni] = __builtin_amdgcn_mfma_f32_16x16x32_bf16(af[mi], bfr[ni], acc[mi][ni], 0, 0, 0);
    }
  }
  __syncthreads();   // all waves done with LDS bufs before h overlays buf0

  // epilogue 1: h = relu(acc + b1) -> h_lds (bf16). C/D layout: col=lane&15, row=quad*4+r
  const float* b1e = b1 + e * H_DIM;
#pragma unroll
  for (int ni = 0; ni < 4; ++ni) {
    const int col  = nhalf + ni * 16 + (lane & 15);
    const float bias = b1e[col];
#pragma unroll
    for (int mi = 0; mi < 4; ++mi) {
      const int rbase = mhalf + mi * 16 + (quad << 2);
#pragma unroll
      for (int r = 0; r < 4; ++r) {
        float v = acc[mi][ni][r] + bias;
        v = v > 0.f ? v : 0.f;
        h_lds[(rbase + r) * HLDS_STRIDE + col] = f2bf(v);
      }
    }
  }
  __syncthreads();

  // epilogue 2: y[128x16] = h[128x128] @ W2[128x16]; wave handles 32 token rows
  f32x4 acc2[2];
  acc2[0] = (f32x4){0.f, 0.f, 0.f, 0.f};
  acc2[1] = (f32x4){0.f, 0.f, 0.f, 0.f};
#pragma unroll
  for (int ks = 0; ks < 4; ++ks) {
    const int krd = ks * 32 + quad * 8;
    bf16x8 bfr = *(const bf16x8*)(w2t_lds + (lane & 15) * 128 + krd);
#pragma unroll
    for (int mi = 0; mi < 2; ++mi) {
      bf16x8 afr = *(const bf16x8*)(h_lds + (wv * 32 + mi * 16 + (lane & 15)) * HLDS_STRIDE + krd);
      acc2[mi] = __builtin_amdgcn_mfma_f32_16x16x32_bf16(afr, bfr, acc2[mi], 0, 0, 0);
    }
  }
  const int o = lane & 15;
  if (o < O_DIM) {
    const float bias2 = b2[e * O_DIM + o];
#pragma unroll
    for (int mi = 0; mi < 2; ++mi) {
#pragma unroll
      for (int r = 0; r < 4; ++r) {
        const int rl = wv * 32 + mi * 16 + (quad << 2) + r;
        if (row0 + rl < n_e)
          ypair[(size_t)(off_e + row0 + rl) * 16 + o] = acc2[mi][r] + bias2;
      }
    }
  }
}

// ---------------- K3: combine top-2 via compact slots ----------------
__global__ __launch_bounds__(256) void k3_combine(
    const float* __restrict__ ypair, const int4* __restrict__ idx4,
    const float2* __restrict__ wts, const int* __restrict__ off_g,
    float* __restrict__ out) {
  const int g = blockIdx.x * 256 + threadIdx.x;
  if (g >= B_TOK * O_DIM) return;
  const int b = g / O_DIM, o = g - b * O_DIM;
  const int4 r = idx4[b];
  const float2 w = wts[b];
  out[g] = w.x * ypair[(size_t)(off_g[r.x] + r.y) * 16 + o] +
           w.y * ypair[(size_t)(off_g[r.z] + r.w) * 16 + o];
}

extern "C" void kernel_launch(void* const* d_in, const int* in_sizes, int n_in,
                              void* d_out, int out_size, void* d_ws, size_t ws_size,
                              hipStream_t stream) {
  const float* x  = (const float*)d_in[0];
  const float* Wg = (const float*)d_in[1];
  const float* bg = (const float*)d_in[2];
  const float* W1 = (const float*)d_in[3];
  const float* b1 = (const float*)d_in[4];
  const float* W2 = (const float*)d_in[5];
  const float* b2 = (const float*)d_in[6];
  float* out = (float*)d_out;

  char* ws = (char*)d_ws;
  unsigned short* xb  = (unsigned short*)ws;                 // 50331648 B
  unsigned short* w1t = (unsigned short*)(ws + 50331648);    // 6291456 B
  int4*   idx4  = (int4*)  (ws + 56623104);                  // 131072 B
  float2* wts   = (float2*)(ws + 56754176);                  // 65536 B
  int*    cnt   = (int*)   (ws + 56819712);                  // 128 B
  int*    off_g = (int*)   (ws + 56819840);                  // 128 B
  int*    tlist = (int*)   (ws + 56819968);                  // 70144 B (padded slots)
  float*  ypair = (float*) (ws + 56890112);                  // 1122304 B

  k0_w1_transpose<<<dim3(48, 2, 8), dim3(256), 0, stream>>>(W1, w1t);
  (void)hipMemsetAsync(cnt, 0, N_EXP * sizeof(int), stream);
  k1_gate_convert<<<dim3(B_TOK / 32), dim3(512), 0, stream>>>(x, Wg, bg, xb, idx4, wts, cnt);
  k1b1_scan<<<dim3(1), dim3(64), 0, stream>>>(cnt, off_g);
  k1b2_scatter<<<dim3(B_TOK / 256), dim3(256), 0, stream>>>(off_g, idx4, tlist);
  k2_experts<<<dim3(B_TOK / BM, N_EXP), dim3(256), 0, stream>>>(
      xb, w1t, b1, W2, b2, cnt, off_g, tlist, ypair);
  k3_combine<<<dim3((B_TOK * O_DIM + 255) / 256), dim3(256), 0, stream>>>(
      ypair, idx4, wts, off_g, out);
}

// Round 6
// 261.524 us; speedup vs baseline: 1.0839x; 1.0348x over previous
//
#include <hip/hip_runtime.h>
#include <hip/hip_bf16.h>

#define B_TOK 8192
#define D_DIM 3072
#define H_DIM 128
#define O_DIM 10
#define N_EXP 8

#define BM 128
#define BK2 128            // K-tile (24 iters over D=3072)
#define HLDS_STRIDE 136    // bf16 elems; row byte stride 272
#define CHK 768            // k1a D-chunk
#define NCHK 4

typedef __bf16 bf16x8 __attribute__((ext_vector_type(8)));
typedef float  f32x4  __attribute__((ext_vector_type(4)));
typedef unsigned short us8 __attribute__((ext_vector_type(8)));

// fp32 -> bf16 round-to-nearest-even
__device__ __forceinline__ unsigned short f2bf(float f) {
  unsigned int u = __float_as_uint(f);
  unsigned int r = (u + 0x7FFFu + ((u >> 16) & 1u)) >> 16;
  return (unsigned short)r;
}

__device__ __forceinline__ void async16(const void* g, void* l) {
  __builtin_amdgcn_global_load_lds(
      (const __attribute__((address_space(1))) void*)g,
      (__attribute__((address_space(3))) void*)l,
      16, 0, 0);
}

// ---------------- K0: W1 [8][3072][128] fp32 -> W1^T [8][128][3072] bf16 ----------------
__global__ __launch_bounds__(256) void k0_w1_transpose(const float* __restrict__ W1,
                                                       unsigned short* __restrict__ w1t) {
  __shared__ __align__(16) unsigned short lds[64 * 72];  // [h][72]
  const int e  = blockIdx.z;
  const int d0 = blockIdx.x * 64;
  const int h0 = blockIdx.y * 64;
  const int tid = threadIdx.x;

  const float* src = W1 + ((size_t)e * D_DIM + d0) * H_DIM + h0;
  const int hl = tid & 63;   // h lane
  const int dg = tid >> 6;   // 0..3
#pragma unroll
  for (int k = 0; k < 16; ++k) {
    const int d = dg + 4 * k;
    lds[hl * 72 + d] = f2bf(src[(size_t)d * H_DIM + hl]);
  }
  __syncthreads();

  unsigned short* dst = w1t + ((size_t)e * H_DIM + h0) * D_DIM + d0;
  const int q  = tid & 7;    // d-oct
  const int h1 = tid >> 3;   // 0..31
#pragma unroll
  for (int k = 0; k < 2; ++k) {
    const int h = h1 + 32 * k;
    const int d = q * 8;
    us8 v = *(const us8*)(lds + h * 72 + d);
    *(us8*)(dst + (size_t)h * D_DIM + d) = v;
  }
}

// ---------------- K1a: stream x -> bf16 + partial gating per D-chunk ----------------
// grid (B/16, NCHK). Block 256 = 4 waves, 4 tokens/wave, chunk of 768 d.
// Wg chunk in LDS as [n][dl] (24 KB) -> ~4-6 blocks/CU, fully independent float4 streams.
__global__ __launch_bounds__(256) void k1a_stream(
    const float* __restrict__ x, const float* __restrict__ Wg,
    unsigned short* __restrict__ xb, float* __restrict__ gpart) {
  __shared__ float wg_lds[N_EXP * CHK];  // 24 KB
  const int c   = blockIdx.y;
  const int d0  = c * CHK;
  const int tid = threadIdx.x;

  // stage Wg chunk: global [d][n] float4 (= one d, 4 experts) -> LDS [n][dl]
  for (int f = tid; f < CHK * N_EXP / 4; f += 256) {
    const float4 v = ((const float4*)(Wg + (size_t)d0 * N_EXP))[f];
    const int dl = f >> 1;
    const int nh = (f & 1) * 4;
    wg_lds[(nh + 0) * CHK + dl] = v.x;
    wg_lds[(nh + 1) * CHK + dl] = v.y;
    wg_lds[(nh + 2) * CHK + dl] = v.z;
    wg_lds[(nh + 3) * CHK + dl] = v.w;
  }
  __syncthreads();

  const int lane = tid & 63;
  const int wv   = tid >> 6;
  const int t0   = blockIdx.x * 16 + wv * 4;

  const float* xr0 = x + (size_t)(t0 + 0) * D_DIM + d0;
  const float* xr1 = x + (size_t)(t0 + 1) * D_DIM + d0;
  const float* xr2 = x + (size_t)(t0 + 2) * D_DIM + d0;
  const float* xr3 = x + (size_t)(t0 + 3) * D_DIM + d0;
  unsigned short* xw0 = xb + (size_t)(t0 + 0) * D_DIM + d0;
  unsigned short* xw1 = xb + (size_t)(t0 + 1) * D_DIM + d0;
  unsigned short* xw2 = xb + (size_t)(t0 + 2) * D_DIM + d0;
  unsigned short* xw3 = xb + (size_t)(t0 + 3) * D_DIM + d0;

  float acc[4][N_EXP];
#pragma unroll
  for (int t = 0; t < 4; ++t)
#pragma unroll
    for (int n = 0; n < N_EXP; ++n) acc[t][n] = 0.f;

#pragma unroll
  for (int s = 0; s < CHK / 256; ++s) {
    const int dl = s * 256 + lane * 4;
    float4 xv0 = *(const float4*)(xr0 + dl);
    float4 xv1 = *(const float4*)(xr1 + dl);
    float4 xv2 = *(const float4*)(xr2 + dl);
    float4 xv3 = *(const float4*)(xr3 + dl);
    float4 w4[N_EXP];
#pragma unroll
    for (int n = 0; n < N_EXP; ++n)
      w4[n] = *(const float4*)(wg_lds + n * CHK + dl);
    ushort4 p;
    p.x = f2bf(xv0.x); p.y = f2bf(xv0.y); p.z = f2bf(xv0.z); p.w = f2bf(xv0.w);
    *(ushort4*)(xw0 + dl) = p;
    p.x = f2bf(xv1.x); p.y = f2bf(xv1.y); p.z = f2bf(xv1.z); p.w = f2bf(xv1.w);
    *(ushort4*)(xw1 + dl) = p;
    p.x = f2bf(xv2.x); p.y = f2bf(xv2.y); p.z = f2bf(xv2.z); p.w = f2bf(xv2.w);
    *(ushort4*)(xw2 + dl) = p;
    p.x = f2bf(xv3.x); p.y = f2bf(xv3.y); p.z = f2bf(xv3.z); p.w = f2bf(xv3.w);
    *(ushort4*)(xw3 + dl) = p;
#pragma unroll
    for (int n = 0; n < N_EXP; ++n) {
      acc[0][n] = fmaf(xv0.x, w4[n].x, acc[0][n]);
      acc[0][n] = fmaf(xv0.y, w4[n].y, acc[0][n]);
      acc[0][n] = fmaf(xv0.z, w4[n].z, acc[0][n]);
      acc[0][n] = fmaf(xv0.w, w4[n].w, acc[0][n]);
      acc[1][n] = fmaf(xv1.x, w4[n].x, acc[1][n]);
      acc[1][n] = fmaf(xv1.y, w4[n].y, acc[1][n]);
      acc[1][n] = fmaf(xv1.z, w4[n].z, acc[1][n]);
      acc[1][n] = fmaf(xv1.w, w4[n].w, acc[1][n]);
      acc[2][n] = fmaf(xv2.x, w4[n].x, acc[2][n]);
      acc[2][n] = fmaf(xv2.y, w4[n].y, acc[2][n]);
      acc[2][n] = fmaf(xv2.z, w4[n].z, acc[2][n]);
      acc[2][n] = fmaf(xv2.w, w4[n].w, acc[2][n]);
      acc[3][n] = fmaf(xv3.x, w4[n].x, acc[3][n]);
      acc[3][n] = fmaf(xv3.y, w4[n].y, acc[3][n]);
      acc[3][n] = fmaf(xv3.z, w4[n].z, acc[3][n]);
      acc[3][n] = fmaf(xv3.w, w4[n].w, acc[3][n]);
    }
  }

#pragma unroll
  for (int t = 0; t < 4; ++t)
#pragma unroll
    for (int n = 0; n < N_EXP; ++n) {
#pragma unroll
      for (int off = 32; off > 0; off >>= 1)
        acc[t][n] += __shfl_xor(acc[t][n], off, 64);
    }
  if (lane == 0) {
#pragma unroll
    for (int t = 0; t < 4; ++t) {
      float* gp = gpart + ((size_t)c * B_TOK + (t0 + t)) * N_EXP;
      *(float4*)(gp)     = make_float4(acc[t][0], acc[t][1], acc[t][2], acc[t][3]);
      *(float4*)(gp + 4) = make_float4(acc[t][4], acc[t][5], acc[t][6], acc[t][7]);
    }
  }
}

// ---------------- K1c: sum chunk partials, top-2 + softmax, counts ----------------
__global__ __launch_bounds__(256) void k1c_topk(
    const float* __restrict__ gpart, const float* __restrict__ bg,
    int4* __restrict__ idx4, float2* __restrict__ wts, int* __restrict__ cnt) {
  __shared__ int lcnt[N_EXP], gbase[N_EXP];
  __shared__ float bgs[N_EXP];
  const int tid = threadIdx.x;
  if (tid < N_EXP) { lcnt[tid] = 0; bgs[tid] = bg[tid]; }
  __syncthreads();
  const int t = blockIdx.x * 256 + tid;

  float g[N_EXP];
#pragma unroll
  for (int n = 0; n < N_EXP; ++n) g[n] = bgs[n];
#pragma unroll
  for (int c = 0; c < NCHK; ++c) {
    const float* gp = gpart + ((size_t)c * B_TOK + t) * N_EXP;
    float4 a = *(const float4*)(gp);
    float4 b = *(const float4*)(gp + 4);
    g[0] += a.x; g[1] += a.y; g[2] += a.z; g[3] += a.w;
    g[4] += b.x; g[5] += b.y; g[6] += b.z; g[7] += b.w;
  }
  int i0 = 0;
#pragma unroll
  for (int n = 1; n < N_EXP; ++n) if (g[n] > g[i0]) i0 = n;
  int i1 = (i0 == 0) ? 1 : 0;
#pragma unroll
  for (int n = 0; n < N_EXP; ++n) if (n != i0 && g[n] > g[i1]) i1 = n;
  const float e1 = expf(g[i1] - g[i0]);
  const float inv = 1.f / (1.f + e1);
  const int lp0 = atomicAdd(&lcnt[i0], 1);
  const int lp1 = atomicAdd(&lcnt[i1], 1);
  __syncthreads();
  if (tid < N_EXP) gbase[tid] = atomicAdd(&cnt[tid], lcnt[tid]);
  __syncthreads();
  idx4[t] = make_int4(i0, gbase[i0] + lp0, i1, gbase[i1] + lp1);
  wts[t]  = make_float2(inv, e1 * inv);
}

// ---------------- K1b1: tiny scan (offsets padded to BM) ----------------
__global__ void k1b1_scan(const int* __restrict__ cnt, int* __restrict__ off_g) {
  if (threadIdx.x == 0) {
    int s = 0;
#pragma unroll
    for (int n = 0; n < N_EXP; ++n) {
      off_g[n] = s;
      s += (cnt[n] + BM - 1) / BM * BM;   // pad each expert region to BM
    }
    off_g[N_EXP] = s;
  }
}

// ---------------- K1b2: scatter token list ----------------
__global__ __launch_bounds__(256) void k1b2_scatter(
    const int* __restrict__ off_g, const int4* __restrict__ idx4,
    int* __restrict__ tlist) {
  const int t = blockIdx.x * 256 + threadIdx.x;
  if (t >= B_TOK) return;
  const int4 r = idx4[t];
  tlist[off_g[r.x] + r.y] = t;
  tlist[off_g[r.z] + r.w] = t;
}

// ---------------- K2: sparse per-expert h=relu(x@W1+b1); y=h@W2+b2 -> ypair ----------------
// BK=128, double-buffered LDS prefetch (depth 1), ping-pong via byte offsets.
__global__ __launch_bounds__(256) void k2_experts(
    const unsigned short* __restrict__ xb,    // [B][D] bf16
    const unsigned short* __restrict__ w1t,   // [N][H][D] bf16
    const float* __restrict__ b1,             // [N][H]
    const float* __restrict__ W2,             // [N][H][O]
    const float* __restrict__ b2,             // [N][O]
    const int* __restrict__ cnt, const int* __restrict__ off_g,
    const int* __restrict__ tlist,
    float* __restrict__ ypair) {              // [padded slots][16]
  const int e    = blockIdx.y;
  const int n_e  = cnt[e];
  const int row0 = blockIdx.x * BM;
  if (row0 >= n_e) return;
  const int off_e = off_g[e];

  __shared__ __align__(16) unsigned short sm[65536 + 2048];
  unsigned short* h_lds   = sm;
  unsigned short* w2t_lds = sm + 65536;

  const int tid  = threadIdx.x;
  const int lane = tid & 63;
  const int wv   = tid >> 6;

  const float* W2e = W2 + (size_t)e * H_DIM * O_DIM;
  for (int idx = tid; idx < 16 * 128; idx += 256) {
    int o = idx >> 7, hh = idx & 127;
    float v = (o < O_DIM) ? W2e[hh * O_DIM + o] : 0.f;
    w2t_lds[idx] = f2bf(v);
  }

  const int mhalf = (wv >> 1) * 64;
  const int nhalf = (wv & 1) * 64;

  f32x4 acc[4][4];
#pragma unroll
  for (int i = 0; i < 4; ++i)
#pragma unroll
    for (int j = 0; j < 4; ++j)
      acc[i][j] = (f32x4){0.f, 0.f, 0.f, 0.f};

  const int quad = lane >> 4;
  const int koff0 = (lane & 15) * 8;
  const unsigned short* Abase[8];
  const unsigned short* Bbase[8];
#pragma unroll
  for (int j = 0; j < 8; ++j) {
    int rloc = wv * 32 + j * 4 + quad;
    int gr = row0 + rloc;
    gr = gr < n_e ? gr : n_e - 1;
    Abase[j] = xb + (size_t)tlist[off_e + gr] * D_DIM + koff0;
    Bbase[j] = w1t + ((size_t)e * H_DIM + rloc) * D_DIM + koff0;
  }

#define STAGE(it, pp)                                                     \
  {                                                                       \
    const int ko = (it) * BK2;                                            \
    unsigned short* abuf = sm + (pp) * 32768;                             \
    unsigned short* bbuf = sm + 16384 + (pp) * 32768;                     \
    _Pragma("unroll")                                                     \
    for (int j = 0; j < 8; ++j) {                                         \
      const int ldsrow = (wv * 32 + j * 4) * BK2;                         \
      async16(Abase[j] + ko, abuf + ldsrow);                              \
      async16(Bbase[j] + ko, bbuf + ldsrow);                              \
    }                                                                     \
  }

  STAGE(0, 0);

  const int NIT = D_DIM / BK2;  // 24
  for (int it = 0; it < NIT; ++it) {
    __syncthreads();
    if (it + 1 < NIT) STAGE(it + 1, (it + 1) & 1);
    const unsigned short* al = sm + (it & 1) * 32768;
    const unsigned short* bl = sm + 16384 + (it & 1) * 32768;
#pragma unroll
    for (int kk = 0; kk < 4; ++kk) {
      const int krd = kk * 32 + quad * 8;
      bf16x8 af[4], bfr[4];
#pragma unroll
      for (int mi = 0; mi < 4; ++mi)
        af[mi] = *(const bf16x8*)(al + (mhalf + mi * 16 + (lane & 15)) * BK2 + krd);
#pragma unroll
      for (int ni = 0; ni < 4; ++ni)
        bfr[ni] = *(const bf16x8*)(bl + (nhalf + ni * 16 + (lane & 15)) * BK2 + krd);
#pragma unroll
      for (int mi = 0; mi < 4; ++mi)
#pragma unroll
        for (int ni = 0; ni < 4; ++ni)
          acc[mi][ni] = __builtin_amdgcn_mfma_f32_16x16x32_bf16(af[mi], bfr[ni], acc[mi][ni], 0, 0, 0);
    }
  }
  __syncthreads();

  const float* b1e = b1 + e * H_DIM;
#pragma unroll
  for (int ni = 0; ni < 4; ++ni) {
    const int col  = nhalf + ni * 16 + (lane & 15);
    const float bias = b1e[col];
#pragma unroll
    for (int mi = 0; mi < 4; ++mi) {
      const int rbase = mhalf + mi * 16 + (quad << 2);
#pragma unroll
      for (int r = 0; r < 4; ++r) {
        float v = acc[mi][ni][r] + bias;
        v = v > 0.f ? v : 0.f;
        h_lds[(rbase + r) * HLDS_STRIDE + col] = f2bf(v);
      }
    }
  }
  __syncthreads();

  f32x4 acc2[2];
  acc2[0] = (f32x4){0.f, 0.f, 0.f, 0.f};
  acc2[1] = (f32x4){0.f, 0.f, 0.f, 0.f};
#pragma unroll
  for (int ks = 0; ks < 4; ++ks) {
    const int krd = ks * 32 + quad * 8;
    bf16x8 bfr = *(const bf16x8*)(w2t_lds + (lane & 15) * 128 + krd);
#pragma unroll
    for (int mi = 0; mi < 2; ++mi) {
      bf16x8 afr = *(const bf16x8*)(h_lds + (wv * 32 + mi * 16 + (lane & 15)) * HLDS_STRIDE + krd);
      acc2[mi] = __builtin_amdgcn_mfma_f32_16x16x32_bf16(afr, bfr, acc2[mi], 0, 0, 0);
    }
  }
  const int o = lane & 15;
  if (o < O_DIM) {
    const float bias2 = b2[e * O_DIM + o];
#pragma unroll
    for (int mi = 0; mi < 2; ++mi) {
#pragma unroll
      for (int r = 0; r < 4; ++r) {
        const int rl = wv * 32 + mi * 16 + (quad << 2) + r;
        if (row0 + rl < n_e)
          ypair[(size_t)(off_e + row0 + rl) * 16 + o] = acc2[mi][r] + bias2;
      }
    }
  }
}

// ---------------- K3: combine top-2 via compact slots ----------------
__global__ __launch_bounds__(256) void k3_combine(
    const float* __restrict__ ypair, const int4* __restrict__ idx4,
    const float2* __restrict__ wts, const int* __restrict__ off_g,
    float* __restrict__ out) {
  const int g = blockIdx.x * 256 + threadIdx.x;
  if (g >= B_TOK * O_DIM) return;
  const int b = g / O_DIM, o = g - b * O_DIM;
  const int4 r = idx4[b];
  const float2 w = wts[b];
  out[g] = w.x * ypair[(size_t)(off_g[r.x] + r.y) * 16 + o] +
           w.y * ypair[(size_t)(off_g[r.z] + r.w) * 16 + o];
}

extern "C" void kernel_launch(void* const* d_in, const int* in_sizes, int n_in,
                              void* d_out, int out_size, void* d_ws, size_t ws_size,
                              hipStream_t stream) {
  const float* x  = (const float*)d_in[0];
  const float* Wg = (const float*)d_in[1];
  const float* bg = (const float*)d_in[2];
  const float* W1 = (const float*)d_in[3];
  const float* b1 = (const float*)d_in[4];
  const float* W2 = (const float*)d_in[5];
  const float* b2 = (const float*)d_in[6];
  float* out = (float*)d_out;

  char* ws = (char*)d_ws;
  unsigned short* xb  = (unsigned short*)ws;                 // 50331648 B
  unsigned short* w1t = (unsigned short*)(ws + 50331648);    // 6291456 B
  int4*   idx4  = (int4*)  (ws + 56623104);                  // 131072 B
  float2* wts   = (float2*)(ws + 56754176);                  // 65536 B
  int*    cnt   = (int*)   (ws + 56819712);                  // 128 B
  int*    off_g = (int*)   (ws + 56819840);                  // 128 B
  // gpart overlays tlist+ypair: gpart dead after k1c; tlist/ypair written after.
  float*  gpart = (float*) (ws + 56890112);                  // 1048576 B (4*8192*8*4)
  int*    tlist = (int*)   (ws + 56890112);                  // 70144 B
  float*  ypair = (float*) (ws + 56960256);                  // 1122304 B

  k0_w1_transpose<<<dim3(48, 2, 8), dim3(256), 0, stream>>>(W1, w1t);
  (void)hipMemsetAsync(cnt, 0, N_EXP * sizeof(int), stream);
  k1a_stream<<<dim3(B_TOK / 16, NCHK), dim3(256), 0, stream>>>(x, Wg, xb, gpart);
  k1c_topk<<<dim3(B_TOK / 256), dim3(256), 0, stream>>>(gpart, bg, idx4, wts, cnt);
  k1b1_scan<<<dim3(1), dim3(64), 0, stream>>>(cnt, off_g);
  k1b2_scatter<<<dim3(B_TOK / 256), dim3(256), 0, stream>>>(off_g, idx4, tlist);
  k2_experts<<<dim3(B_TOK / BM, N_EXP), dim3(256), 0, stream>>>(
      xb, w1t, b1, W2, b2, cnt, off_g, tlist, ypair);
  k3_combine<<<dim3((B_TOK * O_DIM + 255) / 256), dim3(256), 0, stream>>>(
      ypair, idx4, wts, off_g, out);
}

// Round 7
// 235.159 us; speedup vs baseline: 1.2054x; 1.1121x over previous
//
#include <hip/hip_runtime.h>
#include <hip/hip_bf16.h>

#define B_TOK 8192
#define D_DIM 3072
#define H_DIM 128
#define O_DIM 10
#define N_EXP 8

#define BM 128
#define BK2 128            // K-tile (24 iters over D=3072)
#define HLDS_STRIDE 136    // bf16 elems; row byte stride 272
#define CHK 768            // k1a D-chunk
#define NCHK 4
#define ESTRIDE 4096       // static slots per expert (>25 sigma above mean 2048)

typedef __bf16 bf16x8 __attribute__((ext_vector_type(8)));
typedef float  f32x4  __attribute__((ext_vector_type(4)));
typedef unsigned short us8 __attribute__((ext_vector_type(8)));

// fp32 -> bf16 round-to-nearest-even
__device__ __forceinline__ unsigned short f2bf(float f) {
  unsigned int u = __float_as_uint(f);
  unsigned int r = (u + 0x7FFFu + ((u >> 16) & 1u)) >> 16;
  return (unsigned short)r;
}

__device__ __forceinline__ void async16(const void* g, void* l) {
  __builtin_amdgcn_global_load_lds(
      (const __attribute__((address_space(1))) void*)g,
      (__attribute__((address_space(3))) void*)l,
      16, 0, 0);
}

// ---------------- K0: W1 [8][3072][128] fp32 -> W1^T [8][128][3072] bf16 ----------------
__global__ __launch_bounds__(256) void k0_w1_transpose(const float* __restrict__ W1,
                                                       unsigned short* __restrict__ w1t) {
  __shared__ __align__(16) unsigned short lds[64 * 72];  // [h][72]
  const int e  = blockIdx.z;
  const int d0 = blockIdx.x * 64;
  const int h0 = blockIdx.y * 64;
  const int tid = threadIdx.x;

  const float* src = W1 + ((size_t)e * D_DIM + d0) * H_DIM + h0;
  const int hl = tid & 63;   // h lane
  const int dg = tid >> 6;   // 0..3
#pragma unroll
  for (int k = 0; k < 16; ++k) {
    const int d = dg + 4 * k;
    lds[hl * 72 + d] = f2bf(src[(size_t)d * H_DIM + hl]);
  }
  __syncthreads();

  unsigned short* dst = w1t + ((size_t)e * H_DIM + h0) * D_DIM + d0;
  const int q  = tid & 7;    // d-oct
  const int h1 = tid >> 3;   // 0..31
#pragma unroll
  for (int k = 0; k < 2; ++k) {
    const int h = h1 + 32 * k;
    const int d = q * 8;
    us8 v = *(const us8*)(lds + h * 72 + d);
    *(us8*)(dst + (size_t)h * D_DIM + d) = v;
  }
}

// ---------------- K1a: stream x -> bf16 + partial gating per D-chunk ----------------
__global__ __launch_bounds__(256) void k1a_stream(
    const float* __restrict__ x, const float* __restrict__ Wg,
    unsigned short* __restrict__ xb, float* __restrict__ gpart) {
  __shared__ float wg_lds[N_EXP * CHK];  // 24 KB
  const int c   = blockIdx.y;
  const int d0  = c * CHK;
  const int tid = threadIdx.x;

  for (int f = tid; f < CHK * N_EXP / 4; f += 256) {
    const float4 v = ((const float4*)(Wg + (size_t)d0 * N_EXP))[f];
    const int dl = f >> 1;
    const int nh = (f & 1) * 4;
    wg_lds[(nh + 0) * CHK + dl] = v.x;
    wg_lds[(nh + 1) * CHK + dl] = v.y;
    wg_lds[(nh + 2) * CHK + dl] = v.z;
    wg_lds[(nh + 3) * CHK + dl] = v.w;
  }
  __syncthreads();

  const int lane = tid & 63;
  const int wv   = tid >> 6;
  const int t0   = blockIdx.x * 16 + wv * 4;

  const float* xr0 = x + (size_t)(t0 + 0) * D_DIM + d0;
  const float* xr1 = x + (size_t)(t0 + 1) * D_DIM + d0;
  const float* xr2 = x + (size_t)(t0 + 2) * D_DIM + d0;
  const float* xr3 = x + (size_t)(t0 + 3) * D_DIM + d0;
  unsigned short* xw0 = xb + (size_t)(t0 + 0) * D_DIM + d0;
  unsigned short* xw1 = xb + (size_t)(t0 + 1) * D_DIM + d0;
  unsigned short* xw2 = xb + (size_t)(t0 + 2) * D_DIM + d0;
  unsigned short* xw3 = xb + (size_t)(t0 + 3) * D_DIM + d0;

  float acc[4][N_EXP];
#pragma unroll
  for (int t = 0; t < 4; ++t)
#pragma unroll
    for (int n = 0; n < N_EXP; ++n) acc[t][n] = 0.f;

#pragma unroll
  for (int s = 0; s < CHK / 256; ++s) {
    const int dl = s * 256 + lane * 4;
    float4 xv0 = *(const float4*)(xr0 + dl);
    float4 xv1 = *(const float4*)(xr1 + dl);
    float4 xv2 = *(const float4*)(xr2 + dl);
    float4 xv3 = *(const float4*)(xr3 + dl);
    float4 w4[N_EXP];
#pragma unroll
    for (int n = 0; n < N_EXP; ++n)
      w4[n] = *(const float4*)(wg_lds + n * CHK + dl);
    ushort4 p;
    p.x = f2bf(xv0.x); p.y = f2bf(xv0.y); p.z = f2bf(xv0.z); p.w = f2bf(xv0.w);
    *(ushort4*)(xw0 + dl) = p;
    p.x = f2bf(xv1.x); p.y = f2bf(xv1.y); p.z = f2bf(xv1.z); p.w = f2bf(xv1.w);
    *(ushort4*)(xw1 + dl) = p;
    p.x = f2bf(xv2.x); p.y = f2bf(xv2.y); p.z = f2bf(xv2.z); p.w = f2bf(xv2.w);
    *(ushort4*)(xw2 + dl) = p;
    p.x = f2bf(xv3.x); p.y = f2bf(xv3.y); p.z = f2bf(xv3.z); p.w = f2bf(xv3.w);
    *(ushort4*)(xw3 + dl) = p;
#pragma unroll
    for (int n = 0; n < N_EXP; ++n) {
      acc[0][n] = fmaf(xv0.x, w4[n].x, acc[0][n]);
      acc[0][n] = fmaf(xv0.y, w4[n].y, acc[0][n]);
      acc[0][n] = fmaf(xv0.z, w4[n].z, acc[0][n]);
      acc[0][n] = fmaf(xv0.w, w4[n].w, acc[0][n]);
      acc[1][n] = fmaf(xv1.x, w4[n].x, acc[1][n]);
      acc[1][n] = fmaf(xv1.y, w4[n].y, acc[1][n]);
      acc[1][n] = fmaf(xv1.z, w4[n].z, acc[1][n]);
      acc[1][n] = fmaf(xv1.w, w4[n].w, acc[1][n]);
      acc[2][n] = fmaf(xv2.x, w4[n].x, acc[2][n]);
      acc[2][n] = fmaf(xv2.y, w4[n].y, acc[2][n]);
      acc[2][n] = fmaf(xv2.z, w4[n].z, acc[2][n]);
      acc[2][n] = fmaf(xv2.w, w4[n].w, acc[2][n]);
      acc[3][n] = fmaf(xv3.x, w4[n].x, acc[3][n]);
      acc[3][n] = fmaf(xv3.y, w4[n].y, acc[3][n]);
      acc[3][n] = fmaf(xv3.z, w4[n].z, acc[3][n]);
      acc[3][n] = fmaf(xv3.w, w4[n].w, acc[3][n]);
    }
  }

#pragma unroll
  for (int t = 0; t < 4; ++t)
#pragma unroll
    for (int n = 0; n < N_EXP; ++n) {
#pragma unroll
      for (int off = 32; off > 0; off >>= 1)
        acc[t][n] += __shfl_xor(acc[t][n], off, 64);
    }
  if (lane == 0) {
#pragma unroll
    for (int t = 0; t < 4; ++t) {
      float* gp = gpart + ((size_t)c * B_TOK + (t0 + t)) * N_EXP;
      *(float4*)(gp)     = make_float4(acc[t][0], acc[t][1], acc[t][2], acc[t][3]);
      *(float4*)(gp + 4) = make_float4(acc[t][4], acc[t][5], acc[t][6], acc[t][7]);
    }
  }
}

// ---------------- K1c: sum partials, top-2 + softmax, counts + DIRECT tlist write ----------------
// Static expert regions (ESTRIDE slots each) -> no scan/scatter kernels needed.
__global__ __launch_bounds__(256) void k1c_topk(
    const float* __restrict__ gpart, const float* __restrict__ bg,
    int4* __restrict__ idx4, float2* __restrict__ wts, int* __restrict__ cnt,
    int* __restrict__ tlist) {
  __shared__ int lcnt[N_EXP], gbase[N_EXP];
  __shared__ float bgs[N_EXP];
  const int tid = threadIdx.x;
  if (tid < N_EXP) { lcnt[tid] = 0; bgs[tid] = bg[tid]; }
  __syncthreads();
  const int t = blockIdx.x * 256 + tid;

  float g[N_EXP];
#pragma unroll
  for (int n = 0; n < N_EXP; ++n) g[n] = bgs[n];
#pragma unroll
  for (int c = 0; c < NCHK; ++c) {
    const float* gp = gpart + ((size_t)c * B_TOK + t) * N_EXP;
    float4 a = *(const float4*)(gp);
    float4 b = *(const float4*)(gp + 4);
    g[0] += a.x; g[1] += a.y; g[2] += a.z; g[3] += a.w;
    g[4] += b.x; g[5] += b.y; g[6] += b.z; g[7] += b.w;
  }
  int i0 = 0;
#pragma unroll
  for (int n = 1; n < N_EXP; ++n) if (g[n] > g[i0]) i0 = n;
  int i1 = (i0 == 0) ? 1 : 0;
#pragma unroll
  for (int n = 0; n < N_EXP; ++n) if (n != i0 && g[n] > g[i1]) i1 = n;
  const float e1 = expf(g[i1] - g[i0]);
  const float inv = 1.f / (1.f + e1);
  const int lp0 = atomicAdd(&lcnt[i0], 1);
  const int lp1 = atomicAdd(&lcnt[i1], 1);
  __syncthreads();
  if (tid < N_EXP) gbase[tid] = atomicAdd(&cnt[tid], lcnt[tid]);
  __syncthreads();
  int p0 = gbase[i0] + lp0; p0 = p0 < ESTRIDE ? p0 : ESTRIDE - 1;
  int p1 = gbase[i1] + lp1; p1 = p1 < ESTRIDE ? p1 : ESTRIDE - 1;
  tlist[i0 * ESTRIDE + p0] = t;
  tlist[i1 * ESTRIDE + p1] = t;
  idx4[t] = make_int4(i0, p0, i1, p1);
  wts[t]  = make_float2(inv, e1 * inv);
}

// ---------------- K2: sparse per-expert h=relu(x@W1+b1); y=h@W2+b2 -> ypair ----------------
// BK=128 dbuf. LDS rows are 256B (bank-degenerate), so blocks are stored with a
// rotate-by-row swizzle: block b of row r lives at position (b + r) mod 16.
// The rotation is applied to each lane's GLOBAL column offset (wave-uniform LDS
// base preserved for global_load_lds); reads apply the inverse -> conflict-free.
__global__ __launch_bounds__(256) void k2_experts(
    const unsigned short* __restrict__ xb,    // [B][D] bf16
    const unsigned short* __restrict__ w1t,   // [N][H][D] bf16
    const float* __restrict__ b1,             // [N][H]
    const float* __restrict__ W2,             // [N][H][O]
    const float* __restrict__ b2,             // [N][O]
    const int* __restrict__ cnt, const int* __restrict__ tlist,
    float* __restrict__ ypair) {              // [N*ESTRIDE][16]
  const int e    = blockIdx.y;
  int n_e        = cnt[e];
  n_e            = n_e < ESTRIDE ? n_e : ESTRIDE;
  const int row0 = blockIdx.x * BM;
  if (row0 >= n_e) return;

  __shared__ __align__(16) unsigned short sm[65536 + 2048];
  unsigned short* h_lds   = sm;
  unsigned short* w2t_lds = sm + 65536;

  const int tid  = threadIdx.x;
  const int lane = tid & 63;
  const int wv   = tid >> 6;
  const int quad = lane >> 4;
  const int cl   = lane & 15;

  // staging bases: lane (quad, cl) stages row j*4+quad, global block (cl - (j*4+quad)) & 15
  const unsigned short* Abase[8];
  const unsigned short* Bbase[8];
#pragma unroll
  for (int j = 0; j < 8; ++j) {
    const int rloc = wv * 32 + j * 4 + quad;
    int gr = row0 + rloc;
    gr = gr < n_e ? gr : n_e - 1;
    const int koff = ((cl - (j * 4 + quad)) & 15) * 8;
    Abase[j] = xb + (size_t)tlist[e * ESTRIDE + gr] * D_DIM + koff;
    Bbase[j] = w1t + ((size_t)e * H_DIM + rloc) * D_DIM + koff;
  }

#define STAGE(it, pp)                                                     \
  {                                                                       \
    const int ko = (it) * BK2;                                            \
    unsigned short* abuf = sm + (pp) * 32768;                             \
    unsigned short* bbuf = sm + 16384 + (pp) * 32768;                     \
    _Pragma("unroll")                                                     \
    for (int j = 0; j < 8; ++j) {                                         \
      const int ldsrow = (wv * 32 + j * 4) * BK2;                         \
      async16(Abase[j] + ko, abuf + ldsrow);                              \
      async16(Bbase[j] + ko, bbuf + ldsrow);                              \
    }                                                                     \
  }

  STAGE(0, 0);

  // stage W2^T swizzled: element (o, hh) -> o*128 + (((hh>>3)+o)&15)*8 + (hh&7)
  const float* W2e = W2 + (size_t)e * H_DIM * O_DIM;
  for (int idx = tid; idx < 16 * 128; idx += 256) {
    const int o = idx >> 7, hh = idx & 127;
    const float v = (o < O_DIM) ? W2e[hh * O_DIM + o] : 0.f;
    w2t_lds[o * 128 + ((((hh >> 3) + o) & 15) * 8) + (hh & 7)] = f2bf(v);
  }

  const int mhalf = (wv >> 1) * 64;
  const int nhalf = (wv & 1) * 64;

  f32x4 acc[4][4];
#pragma unroll
  for (int i = 0; i < 4; ++i)
#pragma unroll
    for (int j = 0; j < 4; ++j)
      acc[i][j] = (f32x4){0.f, 0.f, 0.f, 0.f};

  const int NIT = D_DIM / BK2;  // 24
  for (int it = 0; it < NIT; ++it) {
    __syncthreads();
    if (it + 1 < NIT) STAGE(it + 1, (it + 1) & 1);
    const unsigned short* al = sm + (it & 1) * 32768;
    const unsigned short* bl = sm + 16384 + (it & 1) * 32768;
#pragma unroll
    for (int kk = 0; kk < 4; ++kk) {
      const int pos = ((kk * 4 + quad + cl) & 15) * 8;  // swizzled k-block
      bf16x8 af[4], bfr[4];
#pragma unroll
      for (int mi = 0; mi < 4; ++mi)
        af[mi] = *(const bf16x8*)(al + (mhalf + mi * 16 + cl) * BK2 + pos);
#pragma unroll
      for (int ni = 0; ni < 4; ++ni)
        bfr[ni] = *(const bf16x8*)(bl + (nhalf + ni * 16 + cl) * BK2 + pos);
#pragma unroll
      for (int mi = 0; mi < 4; ++mi)
#pragma unroll
        for (int ni = 0; ni < 4; ++ni)
          acc[mi][ni] = __builtin_amdgcn_mfma_f32_16x16x32_bf16(af[mi], bfr[ni], acc[mi][ni], 0, 0, 0);
    }
  }
  __syncthreads();

  // epilogue 1: h = relu(acc + b1) -> h_lds (bf16). C/D layout: col=lane&15, row=quad*4+r
  const float* b1e = b1 + e * H_DIM;
#pragma unroll
  for (int ni = 0; ni < 4; ++ni) {
    const int col  = nhalf + ni * 16 + cl;
    const float bias = b1e[col];
#pragma unroll
    for (int mi = 0; mi < 4; ++mi) {
      const int rbase = mhalf + mi * 16 + (quad << 2);
#pragma unroll
      for (int r = 0; r < 4; ++r) {
        float v = acc[mi][ni][r] + bias;
        v = v > 0.f ? v : 0.f;
        h_lds[(rbase + r) * HLDS_STRIDE + col] = f2bf(v);
      }
    }
  }
  __syncthreads();

  // epilogue 2: y[128x16] = h[128x128] @ W2[128x16]
  f32x4 acc2[2];
  acc2[0] = (f32x4){0.f, 0.f, 0.f, 0.f};
  acc2[1] = (f32x4){0.f, 0.f, 0.f, 0.f};
#pragma unroll
  for (int ks = 0; ks < 4; ++ks) {
    const int krd = ks * 32 + quad * 8;
    bf16x8 bfr = *(const bf16x8*)(w2t_lds + cl * 128 + ((ks * 4 + quad + cl) & 15) * 8);
#pragma unroll
    for (int mi = 0; mi < 2; ++mi) {
      bf16x8 afr = *(const bf16x8*)(h_lds + (wv * 32 + mi * 16 + cl) * HLDS_STRIDE + krd);
      acc2[mi] = __builtin_amdgcn_mfma_f32_16x16x32_bf16(afr, bfr, acc2[mi], 0, 0, 0);
    }
  }
  const int o = cl;
  if (o < O_DIM) {
    const float bias2 = b2[e * O_DIM + o];
#pragma unroll
    for (int mi = 0; mi < 2; ++mi) {
#pragma unroll
      for (int r = 0; r < 4; ++r) {
        const int rl = wv * 32 + mi * 16 + (quad << 2) + r;
        if (row0 + rl < n_e)
          ypair[(size_t)(e * ESTRIDE + row0 + rl) * 16 + o] = acc2[mi][r] + bias2;
      }
    }
  }
}

// ---------------- K3: combine top-2 via static slots ----------------
__global__ __launch_bounds__(256) void k3_combine(
    const float* __restrict__ ypair, const int4* __restrict__ idx4,
    const float2* __restrict__ wts, float* __restrict__ out) {
  const int g = blockIdx.x * 256 + threadIdx.x;
  if (g >= B_TOK * O_DIM) return;
  const int b = g / O_DIM, o = g - b * O_DIM;
  const int4 r = idx4[b];
  const float2 w = wts[b];
  out[g] = w.x * ypair[(size_t)(r.x * ESTRIDE + r.y) * 16 + o] +
           w.y * ypair[(size_t)(r.z * ESTRIDE + r.w) * 16 + o];
}

extern "C" void kernel_launch(void* const* d_in, const int* in_sizes, int n_in,
                              void* d_out, int out_size, void* d_ws, size_t ws_size,
                              hipStream_t stream) {
  const float* x  = (const float*)d_in[0];
  const float* Wg = (const float*)d_in[1];
  const float* bg = (const float*)d_in[2];
  const float* W1 = (const float*)d_in[3];
  const float* b1 = (const float*)d_in[4];
  const float* W2 = (const float*)d_in[5];
  const float* b2 = (const float*)d_in[6];
  float* out = (float*)d_out;

  char* ws = (char*)d_ws;
  unsigned short* xb  = (unsigned short*)ws;                 // 50331648 B
  unsigned short* w1t = (unsigned short*)(ws + 50331648);    // 6291456 B
  int4*   idx4  = (int4*)  (ws + 56623104);                  // 131072 B
  float2* wts   = (float2*)(ws + 56754176);                  // 65536 B
  int*    cnt   = (int*)   (ws + 56819712);                  // 128 B
  int*    tlist = (int*)   (ws + 56819840);                  // 131072 B (8*4096*4)
  // gpart (1 MB) overlays ypair: gpart dead after k1c; ypair written by k2 (after).
  float*  gpart = (float*) (ws + 56950912);
  float*  ypair = (float*) (ws + 56950912);                  // 2097152 B (8*4096*16*4)
                                                             // total ~59.05 MB

  k0_w1_transpose<<<dim3(48, 2, 8), dim3(256), 0, stream>>>(W1, w1t);
  (void)hipMemsetAsync(cnt, 0, N_EXP * sizeof(int), stream);
  k1a_stream<<<dim3(B_TOK / 16, NCHK), dim3(256), 0, stream>>>(x, Wg, xb, gpart);
  k1c_topk<<<dim3(B_TOK / 256), dim3(256), 0, stream>>>(gpart, bg, idx4, wts, cnt, tlist);
  k2_experts<<<dim3(ESTRIDE / BM, N_EXP), dim3(256), 0, stream>>>(
      xb, w1t, b1, W2, b2, cnt, tlist, ypair);
  k3_combine<<<dim3((B_TOK * O_DIM + 255) / 256), dim3(256), 0, stream>>>(
      ypair, idx4, wts, out);
}